// Round 1
// baseline (3753.723 us; speedup 1.0000x reference)
//
#include <hip/hip_runtime.h>
#include <hip/hip_bf16.h>
#include <math.h>

#define B_ 2
#define T_ 2048
#define D_ 2048
#define H_ 16

// ---------------------------------------------------------------------------
// fp32 SGEMM: C[M,N] = A[M,K] @ B[K,N], all row-major. 128x128 tile, 256 thr,
// 8x8 per thread, K-step 8. A staged transposed in LDS.
// Requires M%128==0, N%128==0, K%8==0.
// ---------------------------------------------------------------------------
__global__ __launch_bounds__(256) void gemm_f32_128(
    const float* __restrict__ A, const float* __restrict__ Bm,
    float* __restrict__ C, int M, int N, int K)
{
    __shared__ float As[8][128];
    __shared__ float Bs[8][128];

    const int tid = threadIdx.x;
    const int ty = tid >> 4, tx = tid & 15;
    const int row0 = blockIdx.y << 7, col0 = blockIdx.x << 7;

    const int ar = tid >> 1;          // 0..127
    const int ak = (tid & 1) << 2;    // 0 or 4
    const int bk = tid >> 5;          // 0..7
    const int bj = (tid & 31) << 2;   // 0..124

    float acc[8][8];
#pragma unroll
    for (int i = 0; i < 8; i++)
#pragma unroll
        for (int j = 0; j < 8; j++) acc[i][j] = 0.f;

    const float* Aptr = A + (size_t)(row0 + ar) * K + ak;
    const float* Bptr = Bm + (size_t)bk * N + col0 + bj;

    for (int k0 = 0; k0 < K; k0 += 8) {
        const float4 av = *(const float4*)(Aptr + k0);
        const float4 bv = *(const float4*)(Bptr + (size_t)k0 * N);
        __syncthreads();
        As[ak + 0][ar] = av.x;
        As[ak + 1][ar] = av.y;
        As[ak + 2][ar] = av.z;
        As[ak + 3][ar] = av.w;
        *(float4*)&Bs[bk][bj] = bv;
        __syncthreads();
#pragma unroll
        for (int kk = 0; kk < 8; kk++) {
            float a[8], b[8];
            *(float4*)&a[0] = *(const float4*)&As[kk][ty << 3];
            *(float4*)&a[4] = *(const float4*)&As[kk][(ty << 3) + 4];
            *(float4*)&b[0] = *(const float4*)&Bs[kk][tx << 3];
            *(float4*)&b[4] = *(const float4*)&Bs[kk][(tx << 3) + 4];
#pragma unroll
            for (int i = 0; i < 8; i++)
#pragma unroll
                for (int j = 0; j < 8; j++) acc[i][j] += a[i] * b[j];
        }
    }

#pragma unroll
    for (int i = 0; i < 8; i++) {
        float* Crow = C + (size_t)(row0 + (ty << 3) + i) * N + col0 + (tx << 3);
        float4 c0 = make_float4(acc[i][0], acc[i][1], acc[i][2], acc[i][3]);
        float4 c1 = make_float4(acc[i][4], acc[i][5], acc[i][6], acc[i][7]);
        *(float4*)&Crow[0] = c0;
        *(float4*)&Crow[4] = c1;
    }
}

// ---------------------------------------------------------------------------
// gate[row,h] = sigmoid(gate_logit[h] + x[row,:] . gate_w[:,h])
// ---------------------------------------------------------------------------
__global__ __launch_bounds__(256) void gate_kernel(
    const float* __restrict__ x, const float* __restrict__ gw,
    const float* __restrict__ glogit, float* __restrict__ gate)
{
    const int gid = blockIdx.x * 256 + threadIdx.x;
    const int row = gid >> 4;
    const int h = gid & 15;
    const float* xr = x + (size_t)row * D_;
    float acc = 0.f;
#pragma unroll 8
    for (int d = 0; d < D_; d++) acc += xr[d] * gw[d * H_ + h];
    const float z = glogit[h] + acc;
    gate[row * H_ + h] = 1.f / (1.f + expf(-z));
}

// ---------------------------------------------------------------------------
// In-place RoPE on q_geo and k_geo ([B*T, H*64] layout, half=32).
// Mirrors the reference's fp32 trig path.
// ---------------------------------------------------------------------------
__global__ __launch_bounds__(256) void rope_kernel(
    float* __restrict__ qg, float* __restrict__ kg)
{
    const int gid = blockIdx.x * 256 + threadIdx.x;  // B*T*H*32 total
    const int j = gid & 31;
    const int h = (gid >> 5) & 15;
    const int row = gid >> 9;        // 0 .. B*T-1
    const int t = row & (T_ - 1);

    const float invf = exp2f((float)j * -0.41524101186091903f);  // 10000^(-j/32)
    const float ang = (float)t * invf;
    const float c = cosf(ang), s = sinf(ang);

    const int base = row * 1024 + h * 64 + j;
    const float x1 = qg[base], x2 = qg[base + 32];
    qg[base]      = x1 * c - x2 * s;
    qg[base + 32] = x2 * c + x1 * s;
    const float y1 = kg[base], y2 = kg[base + 32];
    kg[base]      = y1 * c - y2 * s;
    kg[base + 32] = y2 * c + y1 * s;
}

// ---------------------------------------------------------------------------
// Causal flash attention over concatenated (sem|geo) 128-dim keys/queries,
// gate folded into the Q rows. QBLK=64, KBLK=32, 256 threads.
// LDS: Qt[128][64] (32KB) + KtP[4096] (16KB, K^T then P) + Vs[32][128] (16KB)
// ---------------------------------------------------------------------------
__global__ __launch_bounds__(256) void attn_kernel(
    const float* __restrict__ QS, const float* __restrict__ KSp,
    const float* __restrict__ QG, const float* __restrict__ KG,
    const float* __restrict__ Vp, const float* __restrict__ GATE,
    float* __restrict__ OUT)
{
    __shared__ float Qt[128][64];
    __shared__ float KtP[4096];
    __shared__ float Vs[32][128];

    const int tid = threadIdx.x;
    const int ty = tid >> 4, tx = tid & 15;
    const int bh = blockIdx.y;
    const int b = bh >> 4, h = bh & 15;
    const int t0 = blockIdx.x << 6;

    // ---- stage Q transposed, gate-scaled: Qt[d][r] ----
    {
        const int r = tid & 63;
        const int grow = b * T_ + t0 + r;
        const float g = GATE[grow * H_ + h];
        const float scs = g * 0.125f;
        const float scg = (1.f - g) * 0.125f;
        const float* qsrow = QS + (size_t)grow * 1024 + h * 64;
        const float* qgrow = QG + (size_t)grow * 1024 + h * 64;
#pragma unroll
        for (int it = 0; it < 8; it++) {
            const int d4 = (tid >> 6) + (it << 2);  // 0..31
            const int d = d4 << 2;
            float4 v4;
            float sc;
            if (d < 64) { v4 = *(const float4*)(qsrow + d); sc = scs; }
            else        { v4 = *(const float4*)(qgrow + d - 64); sc = scg; }
            Qt[d + 0][r] = v4.x * sc;
            Qt[d + 1][r] = v4.y * sc;
            Qt[d + 2][r] = v4.z * sc;
            Qt[d + 3][r] = v4.w * sc;
        }
    }

    float o[4][8];
    float m_i[4], l_i[4];
#pragma unroll
    for (int i = 0; i < 4; i++) {
        m_i[i] = -1e30f;
        l_i[i] = 0.f;
#pragma unroll
        for (int j = 0; j < 8; j++) o[i][j] = 0.f;
    }

    const int nkt = (t0 >> 5) + 2;
    for (int kt = 0; kt < nkt; kt++) {
        const int s0 = kt << 5;
        __syncthreads();  // Qt ready / previous tile's P+V consumed

        // ---- stage K^T: KtP[d*32 + j] ----
        {
            const int j = tid & 31;
            const int grow = b * T_ + s0 + j;
            const float* ksrow = KSp + (size_t)grow * 1024 + h * 64;
            const float* kgrow = KG + (size_t)grow * 1024 + h * 64;
#pragma unroll
            for (int it = 0; it < 4; it++) {
                const int d4 = (tid >> 5) + (it << 3);  // 0..31
                const int d = d4 << 2;
                float4 v4;
                if (d < 64) v4 = *(const float4*)(ksrow + d);
                else        v4 = *(const float4*)(kgrow + d - 64);
                KtP[(d + 0) * 32 + j] = v4.x;
                KtP[(d + 1) * 32 + j] = v4.y;
                KtP[(d + 2) * 32 + j] = v4.z;
                KtP[(d + 3) * 32 + j] = v4.w;
            }
        }
        // ---- stage V row-major: Vs[k][dv] ----
        {
            const int k = tid >> 5;       // 0..7
            const int d4 = tid & 31;
            const float* vrow0 = Vp + (size_t)(b * T_ + s0) * 2048 + h * 128 + (d4 << 2);
#pragma unroll
            for (int it = 0; it < 4; it++) {
                *(float4*)&Vs[k + (it << 3)][d4 << 2] =
                    *(const float4*)(vrow0 + (size_t)(k + (it << 3)) * 2048);
            }
        }
        __syncthreads();

        // ---- S = Qcat . Kcat^T  (4 rows x 2 cols per thread) ----
        float sv[4][2];
        sv[0][0] = sv[0][1] = sv[1][0] = sv[1][1] = 0.f;
        sv[2][0] = sv[2][1] = sv[3][0] = sv[3][1] = 0.f;
#pragma unroll 8
        for (int d = 0; d < 128; d++) {
            const float4 q4 = *(const float4*)&Qt[d][ty << 2];
            const float2 k2 = *(const float2*)&KtP[(d << 5) + (tx << 1)];
            sv[0][0] += q4.x * k2.x; sv[0][1] += q4.x * k2.y;
            sv[1][0] += q4.y * k2.x; sv[1][1] += q4.y * k2.y;
            sv[2][0] += q4.z * k2.x; sv[2][1] += q4.z * k2.y;
            sv[3][0] += q4.w * k2.x; sv[3][1] += q4.w * k2.y;
        }
        // causal mask (only the last two tiles can intersect the diagonal)
        if (kt >= nkt - 2) {
#pragma unroll
            for (int i = 0; i < 4; i++) {
                const int rowt = t0 + (ty << 2) + i;
#pragma unroll
                for (int j = 0; j < 2; j++) {
                    const int cols = s0 + (tx << 1) + j;
                    if (cols > rowt) sv[i][j] = -1e30f;
                }
            }
        }
        __syncthreads();  // done reading K^T; region becomes P

        // ---- online softmax (row groups = 16 lanes) + write P ----
#pragma unroll
        for (int i = 0; i < 4; i++) {
            float mt = fmaxf(sv[i][0], sv[i][1]);
            mt = fmaxf(mt, __shfl_xor(mt, 1, 64));
            mt = fmaxf(mt, __shfl_xor(mt, 2, 64));
            mt = fmaxf(mt, __shfl_xor(mt, 4, 64));
            mt = fmaxf(mt, __shfl_xor(mt, 8, 64));
            const float mnew = fmaxf(m_i[i], mt);
            const float alpha = expf(m_i[i] - mnew);
            const float p0 = expf(sv[i][0] - mnew);
            const float p1 = expf(sv[i][1] - mnew);
            float rs = p0 + p1;
            rs += __shfl_xor(rs, 1, 64);
            rs += __shfl_xor(rs, 2, 64);
            rs += __shfl_xor(rs, 4, 64);
            rs += __shfl_xor(rs, 8, 64);
            l_i[i] = l_i[i] * alpha + rs;
            m_i[i] = mnew;
#pragma unroll
            for (int c = 0; c < 8; c++) o[i][c] *= alpha;
            KtP[((ty << 2) + i) * 33 + (tx << 1) + 0] = p0;
            KtP[((ty << 2) + i) * 33 + (tx << 1) + 1] = p1;
        }
        __syncthreads();

        // ---- O += P @ V  (4 rows x 8 cols per thread) ----
#pragma unroll 4
        for (int k = 0; k < 32; k++) {
            const float4 va = *(const float4*)&Vs[k][tx << 3];
            const float4 vb = *(const float4*)&Vs[k][(tx << 3) + 4];
#pragma unroll
            for (int i = 0; i < 4; i++) {
                const float p = KtP[((ty << 2) + i) * 33 + k];
                o[i][0] += p * va.x; o[i][1] += p * va.y;
                o[i][2] += p * va.z; o[i][3] += p * va.w;
                o[i][4] += p * vb.x; o[i][5] += p * vb.y;
                o[i][6] += p * vb.z; o[i][7] += p * vb.w;
            }
        }
    }

    // ---- epilogue: normalize, write [b, t, h*128 + dv] ----
#pragma unroll
    for (int i = 0; i < 4; i++) {
        const float inv = 1.f / l_i[i];
        float* orow = OUT + (size_t)(b * T_ + t0 + (ty << 2) + i) * 2048 + h * 128 + (tx << 3);
        float4 w0 = make_float4(o[i][0] * inv, o[i][1] * inv, o[i][2] * inv, o[i][3] * inv);
        float4 w1 = make_float4(o[i][4] * inv, o[i][5] * inv, o[i][6] * inv, o[i][7] * inv);
        *(float4*)&orow[0] = w0;
        *(float4*)&orow[4] = w1;
    }
}

// ---------------------------------------------------------------------------
extern "C" void kernel_launch(void* const* d_in, const int* in_sizes, int n_in,
                              void* d_out, int out_size, void* d_ws, size_t ws_size,
                              hipStream_t stream)
{
    const float* x       = (const float*)d_in[0];
    const float* w_q_sem = (const float*)d_in[1];
    const float* w_k_sem = (const float*)d_in[2];
    const float* w_q_geo = (const float*)d_in[3];
    const float* w_k_geo = (const float*)d_in[4];
    const float* w_v     = (const float*)d_in[5];
    const float* w_out   = (const float*)d_in[6];
    const float* glogit  = (const float*)d_in[7];
    const float* gw      = (const float*)d_in[8];
    float* out = (float*)d_out;

    float* ws = (float*)d_ws;
    const size_t SZ_QK = (size_t)B_ * T_ * 1024;      // 4,194,304 floats
    float* QSb  = ws;
    float* KSb  = QSb + SZ_QK;
    float* QGb  = KSb + SZ_QK;
    float* KGb  = QGb + SZ_QK;
    float* Vb   = KGb + SZ_QK;                        // B*T*2048
    float* GATE = Vb + (size_t)B_ * T_ * 2048;        // B*T*H
    float* ATT  = GATE + (size_t)B_ * T_ * H_;        // B*T*2048
    // total: 33,619,968 floats = ~128.3 MiB of workspace

    const int M = B_ * T_;  // 4096
    dim3 blk(256);

    gemm_f32_128<<<dim3(8, 32), blk, 0, stream>>>(x, w_q_sem, QSb, M, 1024, 2048);
    gemm_f32_128<<<dim3(8, 32), blk, 0, stream>>>(x, w_k_sem, KSb, M, 1024, 2048);
    gemm_f32_128<<<dim3(8, 32), blk, 0, stream>>>(x, w_q_geo, QGb, M, 1024, 2048);
    gemm_f32_128<<<dim3(8, 32), blk, 0, stream>>>(x, w_k_geo, KGb, M, 1024, 2048);
    gemm_f32_128<<<dim3(16, 32), blk, 0, stream>>>(x, w_v, Vb, M, 2048, 2048);
    gate_kernel<<<dim3(M * H_ / 256), blk, 0, stream>>>(x, gw, glogit, GATE);
    rope_kernel<<<dim3(M * 512 / 256), blk, 0, stream>>>(QGb, KGb);
    attn_kernel<<<dim3(T_ / 64, B_ * H_), blk, 0, stream>>>(QSb, KSb, QGb, KGb, Vb, GATE, ATT);
    gemm_f32_128<<<dim3(16, 32), blk, 0, stream>>>(ATT, w_out, out, M, 2048, 2048);
}

// Round 2
// 1693.472 us; speedup vs baseline: 2.2166x; 2.2166x over previous
//
#include <hip/hip_runtime.h>
#include <hip/hip_bf16.h>
#include <math.h>

#define B_ 2
#define T_ 2048
#define D_ 2048
#define H_ 16

typedef __attribute__((ext_vector_type(8))) short bf16x8;
typedef __attribute__((ext_vector_type(4))) float f32x4;
typedef unsigned short ushort_t;

// fp32 -> bf16 bits, round-to-nearest-even (matches HW/jax cast)
__device__ __forceinline__ ushort_t f2bf(float f) {
    unsigned int u = __float_as_uint(f);
    u += 0x7fffu + ((u >> 16) & 1u);
    return (ushort_t)(u >> 16);
}

__device__ __forceinline__ void gl_lds16(const void* g, void* l) {
    __builtin_amdgcn_global_load_lds(
        (const __attribute__((address_space(1))) void*)g,
        (__attribute__((address_space(3))) void*)l, 16, 0, 0);
}

// ---------------------------------------------------------------------------
// cvt: fp32 row-major -> bf16 bits row-major (8 elems/thread)
// ---------------------------------------------------------------------------
__global__ __launch_bounds__(256) void cvt_bf16(
    const float* __restrict__ in, ushort_t* __restrict__ out)
{
    const int base = (blockIdx.x * 256 + threadIdx.x) * 8;
    const float4 a = *(const float4*)(in + base);
    const float4 b = *(const float4*)(in + base + 4);
    unsigned int r0 = (unsigned int)f2bf(a.x) | ((unsigned int)f2bf(a.y) << 16);
    unsigned int r1 = (unsigned int)f2bf(a.z) | ((unsigned int)f2bf(a.w) << 16);
    unsigned int r2 = (unsigned int)f2bf(b.x) | ((unsigned int)f2bf(b.y) << 16);
    unsigned int r3 = (unsigned int)f2bf(b.z) | ((unsigned int)f2bf(b.w) << 16);
    *(uint4*)(out + base) = make_uint4(r0, r1, r2, r3);
}

// ---------------------------------------------------------------------------
// cvt + transpose: in[K][N] fp32 -> out[N][K] bf16 bits. 64x64 LDS tile.
// grid: (N/64, K/64), block 256.
// ---------------------------------------------------------------------------
__global__ __launch_bounds__(256) void cvt_tr_bf16(
    const float* __restrict__ in, ushort_t* __restrict__ out, int K, int N)
{
    __shared__ float t[64][65];
    const int n0 = blockIdx.x * 64, k0 = blockIdx.y * 64;
    const int tx = threadIdx.x & 63, ty = threadIdx.x >> 6;  // ty 0..3
#pragma unroll
    for (int i = 0; i < 16; i++) {
        const int r = i * 4 + ty;
        t[r][tx] = in[(size_t)(k0 + r) * N + n0 + tx];
    }
    __syncthreads();
#pragma unroll
    for (int i = 0; i < 16; i++) {
        const int nn = i * 4 + ty;
        out[(size_t)(n0 + nn) * K + k0 + tx] = f2bf(t[tx][nn]);
    }
}

// ---------------------------------------------------------------------------
// bf16 MFMA GEMM (m97 structure): C[M,N] = A[M,K] @ B[K,N], fp32 out.
// A row-major bf16 [M][K]; BT = B transposed bf16 [N][K]. 128x128 tile, BK=32,
// 4 waves (2x2 of 64x64), 16x16x32 MFMA, global_load_lds width 16.
// ---------------------------------------------------------------------------
__global__ __launch_bounds__(256) void gemm_bf16_bt(
    const ushort_t* __restrict__ Ab, const ushort_t* __restrict__ BTb,
    float* __restrict__ C, int M, int N, int K)
{
    __shared__ ushort_t As[4096];  // [128][32]
    __shared__ ushort_t Bs[4096];  // [128][32] (rows = N-cols of C)

    const int tid = threadIdx.x;
    const int w = tid >> 6, lane = tid & 63;
    const int wr = w >> 1, wc = w & 1;
    const int row0 = blockIdx.y << 7, col0 = blockIdx.x << 7;
    const int lm = lane & 15, lk = (lane >> 4) << 3;

    f32x4 acc[4][4];
#pragma unroll
    for (int m = 0; m < 4; m++)
#pragma unroll
        for (int n = 0; n < 4; n++) {
            acc[m][n][0] = 0.f; acc[m][n][1] = 0.f;
            acc[m][n][2] = 0.f; acc[m][n][3] = 0.f;
        }

    for (int k0 = 0; k0 < K; k0 += 32) {
        __syncthreads();  // prior tile's reads complete
#pragma unroll
        for (int i = 0; i < 2; i++) {
            const int chunk = i * 4 + w;           // 0..7
            const int idx = chunk * 64 + lane;     // 0..511
            const int r = idx >> 2;                // 0..127
            const int c = (idx & 3) << 3;          // 0,8,16,24
            gl_lds16(Ab + (size_t)(row0 + r) * K + k0 + c, As + chunk * 512);
            gl_lds16(BTb + (size_t)(col0 + r) * K + k0 + c, Bs + chunk * 512);
        }
        __syncthreads();  // vmcnt(0) drain before barrier -> LDS ready

        bf16x8 av[4], bv[4];
#pragma unroll
        for (int m = 0; m < 4; m++)
            av[m] = *(const bf16x8*)&As[(wr * 64 + m * 16 + lm) * 32 + lk];
#pragma unroll
        for (int n = 0; n < 4; n++)
            bv[n] = *(const bf16x8*)&Bs[(wc * 64 + n * 16 + lm) * 32 + lk];
#pragma unroll
        for (int m = 0; m < 4; m++)
#pragma unroll
            for (int n = 0; n < 4; n++)
                acc[m][n] = __builtin_amdgcn_mfma_f32_16x16x32_bf16(
                    av[m], bv[n], acc[m][n], 0, 0, 0);
    }

    // C/D layout: col = lane&15, row = (lane>>4)*4 + reg
#pragma unroll
    for (int m = 0; m < 4; m++) {
        const int rowb = row0 + wr * 64 + m * 16 + ((lane >> 4) << 2);
#pragma unroll
        for (int n = 0; n < 4; n++) {
            const int col = col0 + wc * 64 + n * 16 + lm;
#pragma unroll
            for (int r = 0; r < 4; r++)
                C[(size_t)(rowb + r) * N + col] = acc[m][n][r];
        }
    }
}

// ---------------------------------------------------------------------------
// gate[row,h] = sigmoid(gate_logit[h] + x[row,:] . gate_w[:,h])
// ---------------------------------------------------------------------------
__global__ __launch_bounds__(256) void gate_kernel(
    const float* __restrict__ x, const float* __restrict__ gw,
    const float* __restrict__ glogit, float* __restrict__ gate)
{
    const int gid = blockIdx.x * 256 + threadIdx.x;
    const int row = gid >> 4;
    const int h = gid & 15;
    const float* xr = x + (size_t)row * D_;
    float acc = 0.f;
#pragma unroll 8
    for (int d = 0; d < D_; d++) acc += xr[d] * gw[d * H_ + h];
    const float z = glogit[h] + acc;
    gate[row * H_ + h] = 1.f / (1.f + expf(-z));
}

// ---------------------------------------------------------------------------
// In-place RoPE on merged QK buffer [B*T][4096]: qg at col 2048, kg at 3072.
// ---------------------------------------------------------------------------
__global__ __launch_bounds__(256) void rope_kernel(float* __restrict__ QK)
{
    const int gid = blockIdx.x * 256 + threadIdx.x;  // B*T*H*32 total
    const int j = gid & 31;
    const int h = (gid >> 5) & 15;
    const int row = gid >> 9;        // 0 .. B*T-1
    const int t = row & (T_ - 1);

    const float invf = exp2f((float)j * -0.41524101186091903f);  // 10000^(-j/32)
    const float ang = (float)t * invf;
    const float c = cosf(ang), s = sinf(ang);

    const int base = row * 4096 + 2048 + h * 64 + j;   // qg
    const int base2 = base + 1024;                      // kg
    const float x1 = QK[base], x2 = QK[base + 32];
    QK[base]      = x1 * c - x2 * s;
    QK[base + 32] = x2 * c + x1 * s;
    const float y1 = QK[base2], y2 = QK[base2 + 32];
    QK[base2]      = y1 * c - y2 * s;
    QK[base2 + 32] = y2 * c + y1 * s;
}

// ---------------------------------------------------------------------------
// Causal flash attention (fp32). QK layout: [B*T][4096] = qs|ks|qg|kg.
// QBLK=64, KBLK=32, 256 threads.
// ---------------------------------------------------------------------------
__global__ __launch_bounds__(256) void attn_kernel(
    const float* __restrict__ QK, const float* __restrict__ Vp,
    const float* __restrict__ GATE, float* __restrict__ OUT)
{
    __shared__ float Qt[128][64];
    __shared__ float KtP[4096];
    __shared__ float Vs[32][128];

    const int tid = threadIdx.x;
    const int ty = tid >> 4, tx = tid & 15;
    const int bh = blockIdx.y;
    const int b = bh >> 4, h = bh & 15;
    const int t0 = blockIdx.x << 6;

    // ---- stage Q transposed, gate-scaled: Qt[d][r] ----
    {
        const int r = tid & 63;
        const int grow = b * T_ + t0 + r;
        const float g = GATE[grow * H_ + h];
        const float scs = g * 0.125f;
        const float scg = (1.f - g) * 0.125f;
        const float* qsrow = QK + (size_t)grow * 4096 + h * 64;
        const float* qgrow = qsrow + 2048;
#pragma unroll
        for (int it = 0; it < 8; it++) {
            const int d4 = (tid >> 6) + (it << 2);  // 0..31
            const int d = d4 << 2;
            float4 v4;
            float sc;
            if (d < 64) { v4 = *(const float4*)(qsrow + d); sc = scs; }
            else        { v4 = *(const float4*)(qgrow + d - 64); sc = scg; }
            Qt[d + 0][r] = v4.x * sc;
            Qt[d + 1][r] = v4.y * sc;
            Qt[d + 2][r] = v4.z * sc;
            Qt[d + 3][r] = v4.w * sc;
        }
    }

    float o[4][8];
    float m_i[4], l_i[4];
#pragma unroll
    for (int i = 0; i < 4; i++) {
        m_i[i] = -1e30f;
        l_i[i] = 0.f;
#pragma unroll
        for (int j = 0; j < 8; j++) o[i][j] = 0.f;
    }

    const int nkt = (t0 >> 5) + 2;
    for (int kt = 0; kt < nkt; kt++) {
        const int s0 = kt << 5;
        __syncthreads();

        // ---- stage K^T: KtP[d*32 + j] ----
        {
            const int j = tid & 31;
            const int grow = b * T_ + s0 + j;
            const float* ksrow = QK + (size_t)grow * 4096 + 1024 + h * 64;
            const float* kgrow = ksrow + 2048;
#pragma unroll
            for (int it = 0; it < 4; it++) {
                const int d4 = (tid >> 5) + (it << 3);  // 0..31
                const int d = d4 << 2;
                float4 v4;
                if (d < 64) v4 = *(const float4*)(ksrow + d);
                else        v4 = *(const float4*)(kgrow + d - 64);
                KtP[(d + 0) * 32 + j] = v4.x;
                KtP[(d + 1) * 32 + j] = v4.y;
                KtP[(d + 2) * 32 + j] = v4.z;
                KtP[(d + 3) * 32 + j] = v4.w;
            }
        }
        // ---- stage V row-major: Vs[k][dv] ----
        {
            const int k = tid >> 5;       // 0..7
            const int d4 = tid & 31;
            const float* vrow0 = Vp + (size_t)(b * T_ + s0) * 2048 + h * 128 + (d4 << 2);
#pragma unroll
            for (int it = 0; it < 4; it++) {
                *(float4*)&Vs[k + (it << 3)][d4 << 2] =
                    *(const float4*)(vrow0 + (size_t)(k + (it << 3)) * 2048);
            }
        }
        __syncthreads();

        // ---- S = Qcat . Kcat^T ----
        float sv[4][2];
        sv[0][0] = sv[0][1] = sv[1][0] = sv[1][1] = 0.f;
        sv[2][0] = sv[2][1] = sv[3][0] = sv[3][1] = 0.f;
#pragma unroll 8
        for (int d = 0; d < 128; d++) {
            const float4 q4 = *(const float4*)&Qt[d][ty << 2];
            const float2 k2 = *(const float2*)&KtP[(d << 5) + (tx << 1)];
            sv[0][0] += q4.x * k2.x; sv[0][1] += q4.x * k2.y;
            sv[1][0] += q4.y * k2.x; sv[1][1] += q4.y * k2.y;
            sv[2][0] += q4.z * k2.x; sv[2][1] += q4.z * k2.y;
            sv[3][0] += q4.w * k2.x; sv[3][1] += q4.w * k2.y;
        }
        if (kt >= nkt - 2) {
#pragma unroll
            for (int i = 0; i < 4; i++) {
                const int rowt = t0 + (ty << 2) + i;
#pragma unroll
                for (int j = 0; j < 2; j++) {
                    const int cols = s0 + (tx << 1) + j;
                    if (cols > rowt) sv[i][j] = -1e30f;
                }
            }
        }
        __syncthreads();

        // ---- online softmax + write P ----
#pragma unroll
        for (int i = 0; i < 4; i++) {
            float mt = fmaxf(sv[i][0], sv[i][1]);
            mt = fmaxf(mt, __shfl_xor(mt, 1, 64));
            mt = fmaxf(mt, __shfl_xor(mt, 2, 64));
            mt = fmaxf(mt, __shfl_xor(mt, 4, 64));
            mt = fmaxf(mt, __shfl_xor(mt, 8, 64));
            const float mnew = fmaxf(m_i[i], mt);
            const float alpha = expf(m_i[i] - mnew);
            const float p0 = expf(sv[i][0] - mnew);
            const float p1 = expf(sv[i][1] - mnew);
            float rs = p0 + p1;
            rs += __shfl_xor(rs, 1, 64);
            rs += __shfl_xor(rs, 2, 64);
            rs += __shfl_xor(rs, 4, 64);
            rs += __shfl_xor(rs, 8, 64);
            l_i[i] = l_i[i] * alpha + rs;
            m_i[i] = mnew;
#pragma unroll
            for (int c = 0; c < 8; c++) o[i][c] *= alpha;
            KtP[((ty << 2) + i) * 33 + (tx << 1) + 0] = p0;
            KtP[((ty << 2) + i) * 33 + (tx << 1) + 1] = p1;
        }
        __syncthreads();

        // ---- O += P @ V ----
#pragma unroll 4
        for (int k = 0; k < 32; k++) {
            const float4 va = *(const float4*)&Vs[k][tx << 3];
            const float4 vb = *(const float4*)&Vs[k][(tx << 3) + 4];
#pragma unroll
            for (int i = 0; i < 4; i++) {
                const float p = KtP[((ty << 2) + i) * 33 + k];
                o[i][0] += p * va.x; o[i][1] += p * va.y;
                o[i][2] += p * va.z; o[i][3] += p * va.w;
                o[i][4] += p * vb.x; o[i][5] += p * vb.y;
                o[i][6] += p * vb.z; o[i][7] += p * vb.w;
            }
        }
    }

#pragma unroll
    for (int i = 0; i < 4; i++) {
        const float inv = 1.f / l_i[i];
        float* orow = OUT + (size_t)(b * T_ + t0 + (ty << 2) + i) * 2048 + h * 128 + (tx << 3);
        float4 w0 = make_float4(o[i][0] * inv, o[i][1] * inv, o[i][2] * inv, o[i][3] * inv);
        float4 w1 = make_float4(o[i][4] * inv, o[i][5] * inv, o[i][6] * inv, o[i][7] * inv);
        *(float4*)&orow[0] = w0;
        *(float4*)&orow[4] = w1;
    }
}

// ---------------------------------------------------------------------------
extern "C" void kernel_launch(void* const* d_in, const int* in_sizes, int n_in,
                              void* d_out, int out_size, void* d_ws, size_t ws_size,
                              hipStream_t stream)
{
    const float* x       = (const float*)d_in[0];
    const float* w_q_sem = (const float*)d_in[1];
    const float* w_k_sem = (const float*)d_in[2];
    const float* w_q_geo = (const float*)d_in[3];
    const float* w_k_geo = (const float*)d_in[4];
    const float* w_v     = (const float*)d_in[5];
    const float* w_out   = (const float*)d_in[6];
    const float* glogit  = (const float*)d_in[7];
    const float* gw      = (const float*)d_in[8];
    float* out = (float*)d_out;

    const int M = B_ * T_;  // 4096
    float* ws = (float*)d_ws;

    // workspace layout (floats):
    float* QK   = ws;                         // [4096][4096] = 16M floats (qs|ks|qg|kg)
    float* Vb   = QK + (size_t)16 * 1024 * 1024;   // [4096][2048] = 8M
    float* ATT  = Vb + (size_t)8 * 1024 * 1024;    // [4096][2048] = 8M
    float* GATE = ATT + (size_t)8 * 1024 * 1024;   // [4096][16]
    ushort_t* WT  = (ushort_t*)(GATE + 65536);     // up to [4096][2048] bf16 = 8M ushort
    ushort_t* xbf = (ushort_t*)ATT;                // [4096][2048] bf16 (dead before attn writes ATT)
    ushort_t* ATTbf = (ushort_t*)QK;               // [4096][2048] bf16 (QK dead after attn)
    // total: 144.25 MB

    dim3 blk(256);

    // x -> bf16
    cvt_bf16<<<dim3(M * 2048 / (256 * 8)), blk, 0, stream>>>(x, xbf);
    // 4 QK-projection weights, transposed+concatenated into WT [4096][2048]
    cvt_tr_bf16<<<dim3(16, 32), blk, 0, stream>>>(w_q_sem, WT + (size_t)0 * 2097152, 2048, 1024);
    cvt_tr_bf16<<<dim3(16, 32), blk, 0, stream>>>(w_k_sem, WT + (size_t)1 * 2097152, 2048, 1024);
    cvt_tr_bf16<<<dim3(16, 32), blk, 0, stream>>>(w_q_geo, WT + (size_t)2 * 2097152, 2048, 1024);
    cvt_tr_bf16<<<dim3(16, 32), blk, 0, stream>>>(w_k_geo, WT + (size_t)3 * 2097152, 2048, 1024);
    // fused QK projection: [4096,2048] @ [2048,4096] -> QK
    gemm_bf16_bt<<<dim3(32, 32), blk, 0, stream>>>(xbf, WT, QK, M, 4096, 2048);
    // V projection
    cvt_tr_bf16<<<dim3(32, 32), blk, 0, stream>>>(w_v, WT, 2048, 2048);
    gemm_bf16_bt<<<dim3(16, 32), blk, 0, stream>>>(xbf, WT, Vb, M, 2048, 2048);
    // gate + rope
    gate_kernel<<<dim3(M * H_ / 256), blk, 0, stream>>>(x, gw, glogit, GATE);
    rope_kernel<<<dim3(M * 512 / 256), blk, 0, stream>>>(QK);
    // attention
    attn_kernel<<<dim3(T_ / 64, B_ * H_), blk, 0, stream>>>(QK, Vb, GATE, ATT);
    // output projection
    cvt_bf16<<<dim3(M * 2048 / (256 * 8)), blk, 0, stream>>>(ATT, ATTbf);
    cvt_tr_bf16<<<dim3(32, 32), blk, 0, stream>>>(w_out, WT, 2048, 2048);
    gemm_bf16_bt<<<dim3(16, 32), blk, 0, stream>>>(ATTbf, WT, out, M, 2048, 2048);
}

// Round 3
// 555.502 us; speedup vs baseline: 6.7574x; 3.0485x over previous
//
#include <hip/hip_runtime.h>
#include <hip/hip_bf16.h>
#include <math.h>

#define B_ 2
#define T_ 2048
#define D_ 2048
#define H_ 16

typedef __attribute__((ext_vector_type(8))) short bf16x8;
typedef __attribute__((ext_vector_type(4))) float f32x4;
typedef unsigned short ushort_t;

// fp32 -> bf16 bits, round-to-nearest-even
__device__ __forceinline__ ushort_t f2bf(float f) {
    unsigned int u = __float_as_uint(f);
    u += 0x7fffu + ((u >> 16) & 1u);
    return (ushort_t)(u >> 16);
}

__device__ __forceinline__ void gl_lds16(const void* g, void* l) {
    __builtin_amdgcn_global_load_lds(
        (const __attribute__((address_space(1))) void*)g,
        (__attribute__((address_space(3))) void*)l, 16, 0, 0);
}

// ---------------------------------------------------------------------------
// cvt: fp32 row-major -> bf16 bits row-major (8 elems/thread)
// ---------------------------------------------------------------------------
__global__ __launch_bounds__(256) void cvt_bf16(
    const float* __restrict__ in, ushort_t* __restrict__ out)
{
    const int base = (blockIdx.x * 256 + threadIdx.x) * 8;
    const float4 a = *(const float4*)(in + base);
    const float4 b = *(const float4*)(in + base + 4);
    unsigned int r0 = (unsigned int)f2bf(a.x) | ((unsigned int)f2bf(a.y) << 16);
    unsigned int r1 = (unsigned int)f2bf(a.z) | ((unsigned int)f2bf(a.w) << 16);
    unsigned int r2 = (unsigned int)f2bf(b.x) | ((unsigned int)f2bf(b.y) << 16);
    unsigned int r3 = (unsigned int)f2bf(b.z) | ((unsigned int)f2bf(b.w) << 16);
    *(uint4*)(out + base) = make_uint4(r0, r1, r2, r3);
}

// ---------------------------------------------------------------------------
// cvt + transpose: in[K][N] fp32 -> out[N][K] bf16 bits. 64x64 LDS tile.
// ---------------------------------------------------------------------------
__global__ __launch_bounds__(256) void cvt_tr_bf16(
    const float* __restrict__ in, ushort_t* __restrict__ out, int K, int N)
{
    __shared__ float t[64][65];
    const int n0 = blockIdx.x * 64, k0 = blockIdx.y * 64;
    const int tx = threadIdx.x & 63, ty = threadIdx.x >> 6;
#pragma unroll
    for (int i = 0; i < 16; i++) {
        const int r = i * 4 + ty;
        t[r][tx] = in[(size_t)(k0 + r) * N + n0 + tx];
    }
    __syncthreads();
#pragma unroll
    for (int i = 0; i < 16; i++) {
        const int nn = i * 4 + ty;
        out[(size_t)(n0 + nn) * K + k0 + tx] = f2bf(t[tx][nn]);
    }
}

// ---------------------------------------------------------------------------
// bf16 MFMA GEMM (m97 structure), 128x128 tile, BK=32, fp32 out.
// ---------------------------------------------------------------------------
__global__ __launch_bounds__(256) void gemm_bf16_bt(
    const ushort_t* __restrict__ Ab, const ushort_t* __restrict__ BTb,
    float* __restrict__ C, int M, int N, int K)
{
    __shared__ ushort_t As[4096];
    __shared__ ushort_t Bs[4096];

    const int tid = threadIdx.x;
    const int w = tid >> 6, lane = tid & 63;
    const int wr = w >> 1, wc = w & 1;
    const int row0 = blockIdx.y << 7, col0 = blockIdx.x << 7;
    const int lm = lane & 15, lk = (lane >> 4) << 3;

    f32x4 acc[4][4];
#pragma unroll
    for (int m = 0; m < 4; m++)
#pragma unroll
        for (int n = 0; n < 4; n++) {
            acc[m][n][0] = 0.f; acc[m][n][1] = 0.f;
            acc[m][n][2] = 0.f; acc[m][n][3] = 0.f;
        }

    for (int k0 = 0; k0 < K; k0 += 32) {
        __syncthreads();
#pragma unroll
        for (int i = 0; i < 2; i++) {
            const int chunk = i * 4 + w;
            const int idx = chunk * 64 + lane;
            const int r = idx >> 2;
            const int c = (idx & 3) << 3;
            gl_lds16(Ab + (size_t)(row0 + r) * K + k0 + c, As + chunk * 512);
            gl_lds16(BTb + (size_t)(col0 + r) * K + k0 + c, Bs + chunk * 512);
        }
        __syncthreads();

        bf16x8 av[4], bv[4];
#pragma unroll
        for (int m = 0; m < 4; m++)
            av[m] = *(const bf16x8*)&As[(wr * 64 + m * 16 + lm) * 32 + lk];
#pragma unroll
        for (int n = 0; n < 4; n++)
            bv[n] = *(const bf16x8*)&Bs[(wc * 64 + n * 16 + lm) * 32 + lk];
#pragma unroll
        for (int m = 0; m < 4; m++)
#pragma unroll
            for (int n = 0; n < 4; n++)
                acc[m][n] = __builtin_amdgcn_mfma_f32_16x16x32_bf16(
                    av[m], bv[n], acc[m][n], 0, 0, 0);
    }

#pragma unroll
    for (int m = 0; m < 4; m++) {
        const int rowb = row0 + wr * 64 + m * 16 + ((lane >> 4) << 2);
#pragma unroll
        for (int n = 0; n < 4; n++) {
            const int col = col0 + wc * 64 + n * 16 + lm;
#pragma unroll
            for (int r = 0; r < 4; r++)
                C[(size_t)(rowb + r) * N + col] = acc[m][n][r];
        }
    }
}

// ---------------------------------------------------------------------------
// gate[row,h] = sigmoid(gate_logit[h] + x[row,:] . gate_w[:,h])
// block per row; x row staged in LDS; 16 chunks x 16 h.
// ---------------------------------------------------------------------------
__global__ __launch_bounds__(256) void gate_kernel(
    const float* __restrict__ x, const float* __restrict__ gw,
    const float* __restrict__ glogit, float* __restrict__ gate)
{
    __shared__ float xs[2048];
    __shared__ float red[256];
    const int row = blockIdx.x, tid = threadIdx.x;
#pragma unroll
    for (int i = 0; i < 8; i++) xs[i * 256 + tid] = x[(size_t)row * 2048 + i * 256 + tid];
    __syncthreads();
    const int h = tid & 15, chunk = tid >> 4;
    float acc = 0.f;
#pragma unroll 4
    for (int d0 = 0; d0 < 128; d0++) {
        const int d = chunk * 128 + d0;
        acc += xs[d] * gw[d * 16 + h];
    }
    red[tid] = acc;
    __syncthreads();
    for (int st = 8; st >= 1; st >>= 1) {
        if (chunk < st) red[chunk * 16 + h] += red[(chunk + st) * 16 + h];
        __syncthreads();
    }
    if (tid < 16) gate[row * 16 + tid] = 1.f / (1.f + expf(-(glogit[tid] + red[tid])));
}

// ---------------------------------------------------------------------------
// rope cos/sin table: tab[t*32+j] = (cos, sin)(t * 10000^(-j/32))
// ---------------------------------------------------------------------------
__global__ __launch_bounds__(256) void rope_table(float2* __restrict__ tab)
{
    const int gid = blockIdx.x * 256 + threadIdx.x;  // 65536
    const int j = gid & 31, t = gid >> 5;
    const float invf = exp2f((float)j * -0.41524101186091903f);
    const float ang = (float)t * invf;
    tab[gid] = make_float2(cosf(ang), sinf(ang));
}

// ---------------------------------------------------------------------------
// prep_qk: QK fp32 [row][4096]=qs|ks|qg|kg + GATE -> per-head bf16 buffers:
//   Qb[bh][t][d]           (gate-scaled, rope'd, x1/8)
//   Kb[bh][t][d ^ ((t&7)<<3)]  (rope'd, XOR-swizzled for LDS)
// one thread per (row, h, j) with j in 0..31.
// ---------------------------------------------------------------------------
__global__ __launch_bounds__(256) void prep_qk(
    const float* __restrict__ QK, const float* __restrict__ GATE,
    const float2* __restrict__ tab,
    ushort_t* __restrict__ Qb, ushort_t* __restrict__ Kb)
{
    const int gid = blockIdx.x * 256 + threadIdx.x;
    const int j = gid & 31;
    const int h = (gid >> 5) & 15;
    const int row = gid >> 9;           // 0..4095
    const int t = row & (T_ - 1);
    const int b = row >> 11;

    const float* base = QK + (size_t)row * 4096 + h * 64 + j;
    const float qs1 = base[0],    qs2 = base[32];
    const float ks1 = base[1024], ks2 = base[1056];
    const float qg1 = base[2048], qg2 = base[2080];
    const float kg1 = base[3072], kg2 = base[3104];

    const float g = GATE[row * 16 + h];
    const float scs = g * 0.125f, scg = (1.f - g) * 0.125f;
    const float2 cs = tab[t * 32 + j];
    const float c = cs.x, s = cs.y;

    const float qo1 = (qg1 * c - qg2 * s) * scg;
    const float qo2 = (qg2 * c + qg1 * s) * scg;
    const float ko1 = kg1 * c - kg2 * s;
    const float ko2 = kg2 * c + kg1 * s;

    const size_t obase = ((size_t)(b * 16 + h) * 2048 + t) * 128;
    Qb[obase + j]       = f2bf(qs1 * scs);
    Qb[obase + j + 32]  = f2bf(qs2 * scs);
    Qb[obase + 64 + j]  = f2bf(qo1);
    Qb[obase + 96 + j]  = f2bf(qo2);
    const int sw = (t & 7) << 3;
    Kb[obase + (j ^ sw)]        = f2bf(ks1);
    Kb[obase + ((j + 32) ^ sw)] = f2bf(ks2);
    Kb[obase + ((64 + j) ^ sw)] = f2bf(ko1);
    Kb[obase + ((96 + j) ^ sw)] = f2bf(ko2);
}

// ---------------------------------------------------------------------------
// prep_v: Vb fp32 [row][h*128+dv] -> Vt[bh][dv][t-tile swizzled] bf16 (V^T).
// 64x64 LDS transpose tiles. grid (T/64, 2, BH).
// ---------------------------------------------------------------------------
__global__ __launch_bounds__(256) void prep_v(
    const float* __restrict__ Vb, ushort_t* __restrict__ Vt)
{
    __shared__ float tile[64][65];
    const int t0 = blockIdx.x * 64, dv0 = blockIdx.y * 64, bh = blockIdx.z;
    const int b = bh >> 4, h = bh & 15;
    const int c = threadIdx.x & 63, rq = threadIdx.x >> 6;
#pragma unroll
    for (int i = 0; i < 16; i++) {
        const int r = i * 4 + rq;
        tile[r][c] = Vb[(size_t)(b * T_ + t0 + r) * 2048 + h * 128 + dv0 + c];
    }
    __syncthreads();
#pragma unroll
    for (int i = 0; i < 16; i++) {
        const int dvr = i * 4 + rq;
        const int dv = dv0 + dvr;
        Vt[((size_t)bh * 128 + dv) * 2048 + t0 + (c ^ ((dv & 7) << 3))] = f2bf(tile[c][dvr]);
    }
}

// ---------------------------------------------------------------------------
// MFMA flash attention. QBLK=128 (4 waves x 32 rows), KBLK=64, d=dv=128.
// K/V^T staged via global_load_lds (pre-swizzled in global); P per-wave LDS.
// Writes bf16 output [b*T+t][h*128+dv] for the out-projection GEMM.
// ---------------------------------------------------------------------------
__global__ __launch_bounds__(256, 2) void attn_mfma(
    const ushort_t* __restrict__ Qb, const ushort_t* __restrict__ Kb,
    const ushort_t* __restrict__ Vt, ushort_t* __restrict__ OUT)
{
    __shared__ ushort_t Ks[64 * 128];   // [key][d_sw]  16KB
    __shared__ ushort_t Vs[128 * 64];   // [dv][k_sw]   16KB
    __shared__ ushort_t Ps[4][32 * 72]; // per-wave P, row stride 72  18KB

    const int tid = threadIdx.x;
    const int w = tid >> 6, l = tid & 63;
    const int lg = l >> 4, lm = l & 15;
    const int bh = blockIdx.y;
    const int t0 = blockIdx.x << 7;
    const size_t hb = (size_t)bh * 2048 * 128;

    // Q fragments (rows t0 + w*32 + m*16 + lm, d = ks*32 + lg*8)
    bf16x8 qf[2][4];
#pragma unroll
    for (int m = 0; m < 2; m++)
#pragma unroll
        for (int ks = 0; ks < 4; ks++)
            qf[m][ks] = *(const bf16x8*)(Qb + hb +
                (size_t)(t0 + w * 32 + m * 16 + lm) * 128 + ks * 32 + lg * 8);

    f32x4 o[2][8];
    float mi[2][4], li[2][4];
#pragma unroll
    for (int m = 0; m < 2; m++) {
#pragma unroll
        for (int r = 0; r < 4; r++) { mi[m][r] = -1e30f; li[m][r] = 0.f; }
#pragma unroll
        for (int nv = 0; nv < 8; nv++) {
            o[m][nv][0] = 0.f; o[m][nv][1] = 0.f; o[m][nv][2] = 0.f; o[m][nv][3] = 0.f;
        }
    }

    ushort_t* pw = &Ps[w][0];
    const int nkt = (t0 >> 6) + 2;

    for (int kt = 0; kt < nkt; kt++) {
        const int s0 = kt << 6;
        __syncthreads();  // all waves done with previous K/V tiles
        // stage K tile: 16 chunks of 1KB; chunk -> rows chunk*4..+3
#pragma unroll
        for (int rr = 0; rr < 4; rr++) {
            const int chunk = rr * 4 + w;
            gl_lds16(Kb + hb + (size_t)(s0 + chunk * 4 + lg) * 128 + lm * 8,
                     Ks + chunk * 512);
        }
        // stage V^T tile: chunk -> dv rows chunk*8..+7 (64 keys each)
#pragma unroll
        for (int rr = 0; rr < 4; rr++) {
            const int chunk = rr * 4 + w;
            gl_lds16(Vt + hb + (size_t)(chunk * 8 + (l >> 3)) * 2048 + s0 + (l & 7) * 8,
                     Vs + chunk * 512);
        }
        __syncthreads();  // vmcnt(0) drain -> LDS ready

        // ---- S = Q . K^T ----
        f32x4 sacc[2][4];
#pragma unroll
        for (int m = 0; m < 2; m++)
#pragma unroll
            for (int n = 0; n < 4; n++) {
                sacc[m][n][0] = 0.f; sacc[m][n][1] = 0.f;
                sacc[m][n][2] = 0.f; sacc[m][n][3] = 0.f;
            }
#pragma unroll
        for (int ks = 0; ks < 4; ks++) {
            bf16x8 bfr[4];
#pragma unroll
            for (int n = 0; n < 4; n++) {
                const int key = n * 16 + lm;
                const int d = ks * 32 + lg * 8;
                bfr[n] = *(const bf16x8*)&Ks[key * 128 + (d ^ ((key & 7) << 3))];
            }
#pragma unroll
            for (int m = 0; m < 2; m++)
#pragma unroll
                for (int n = 0; n < 4; n++)
                    sacc[m][n] = __builtin_amdgcn_mfma_f32_16x16x32_bf16(
                        qf[m][ks], bfr[n], sacc[m][n], 0, 0, 0);
        }

        // ---- causal mask (last two tiles only) ----
        if (kt >= nkt - 2) {
#pragma unroll
            for (int m = 0; m < 2; m++)
#pragma unroll
                for (int n = 0; n < 4; n++)
#pragma unroll
                    for (int r = 0; r < 4; r++) {
                        const int rowt = t0 + w * 32 + m * 16 + lg * 4 + r;
                        const int colt = s0 + n * 16 + lm;
                        if (colt > rowt) sacc[m][n][r] = -1e30f;
                    }
        }

        // ---- online softmax + P -> LDS (bf16) ----
#pragma unroll
        for (int m = 0; m < 2; m++) {
#pragma unroll
            for (int r = 0; r < 4; r++) {
                float mt = fmaxf(fmaxf(sacc[0 + m][0][r], sacc[m][1][r]),
                                 fmaxf(sacc[m][2][r], sacc[m][3][r]));
                mt = fmaxf(mt, __shfl_xor(mt, 1));
                mt = fmaxf(mt, __shfl_xor(mt, 2));
                mt = fmaxf(mt, __shfl_xor(mt, 4));
                mt = fmaxf(mt, __shfl_xor(mt, 8));
                const float mnew = fmaxf(mi[m][r], mt);
                const float alpha = __expf(mi[m][r] - mnew);
                float rs = 0.f;
#pragma unroll
                for (int n = 0; n < 4; n++) {
                    const float p = __expf(sacc[m][n][r] - mnew);
                    sacc[m][n][r] = p;
                    rs += p;
                }
                rs += __shfl_xor(rs, 1);
                rs += __shfl_xor(rs, 2);
                rs += __shfl_xor(rs, 4);
                rs += __shfl_xor(rs, 8);
                li[m][r] = li[m][r] * alpha + rs;
                mi[m][r] = mnew;
#pragma unroll
                for (int nv = 0; nv < 8; nv++) o[m][nv][r] *= alpha;
#pragma unroll
                for (int n = 0; n < 4; n++)
                    pw[(m * 16 + lg * 4 + r) * 72 + n * 16 + lm] = f2bf(sacc[m][n][r]);
            }
        }

        // ---- O += P @ V ----
#pragma unroll
        for (int ks2 = 0; ks2 < 2; ks2++) {
            bf16x8 pa[2];
#pragma unroll
            for (int m = 0; m < 2; m++)
                pa[m] = *(const bf16x8*)&pw[(m * 16 + lm) * 72 + ks2 * 32 + lg * 8];
#pragma unroll
            for (int nv = 0; nv < 8; nv++) {
                const int dv = nv * 16 + lm;
                const bf16x8 vb = *(const bf16x8*)&Vs[dv * 64 +
                    ((ks2 * 32 + lg * 8) ^ ((dv & 7) << 3))];
#pragma unroll
                for (int m = 0; m < 2; m++)
                    o[m][nv] = __builtin_amdgcn_mfma_f32_16x16x32_bf16(
                        pa[m], vb, o[m][nv], 0, 0, 0);
            }
        }
    }

    // ---- epilogue: normalize, write bf16 [b*T+t][h*128+dv] ----
    const int b = bh >> 4, h = bh & 15;
#pragma unroll
    for (int m = 0; m < 2; m++)
#pragma unroll
        for (int r = 0; r < 4; r++) {
            const float inv = 1.f / li[m][r];
            const int trow = t0 + w * 32 + m * 16 + lg * 4 + r;
            ushort_t* orow = OUT + (size_t)(b * T_ + trow) * 2048 + h * 128 + lm;
#pragma unroll
            for (int nv = 0; nv < 8; nv++)
                orow[nv * 16] = f2bf(o[m][nv][r] * inv);
        }
}

// ---------------------------------------------------------------------------
extern "C" void kernel_launch(void* const* d_in, const int* in_sizes, int n_in,
                              void* d_out, int out_size, void* d_ws, size_t ws_size,
                              hipStream_t stream)
{
    const float* x       = (const float*)d_in[0];
    const float* w_q_sem = (const float*)d_in[1];
    const float* w_k_sem = (const float*)d_in[2];
    const float* w_q_geo = (const float*)d_in[3];
    const float* w_k_geo = (const float*)d_in[4];
    const float* w_v     = (const float*)d_in[5];
    const float* w_out   = (const float*)d_in[6];
    const float* glogit  = (const float*)d_in[7];
    const float* gw      = (const float*)d_in[8];
    float* out = (float*)d_out;

    const int M = B_ * T_;  // 4096
    float* ws = (float*)d_ws;

    // workspace layout:
    float* QK   = ws;                                // [4096][4096] fp32 (64MB)
    float* Vb   = QK + (size_t)16 * 1024 * 1024;     // [4096][2048] fp32 (32MB)
    float* GATE = Vb + (size_t)8 * 1024 * 1024;      // [4096][16] (0.25MB)
    ushort_t* WT  = (ushort_t*)(GATE + 65536);       // 16MB bf16 (weights^T)
    ushort_t* xbf = WT + (size_t)8 * 1024 * 1024;    // 16MB bf16
    ushort_t* Qb  = xbf + (size_t)8 * 1024 * 1024;   // 16MB bf16 [bh][t][128]
    float2* ROPETAB = (float2*)(Qb + (size_t)8 * 1024 * 1024);  // 0.5MB
    ushort_t* Kb  = xbf;            // alias: xbf dead after V-GEMM
    ushort_t* Vt  = WT;             // alias: WT(w_v) dead after V-GEMM; re-cvt w_out after attn
    ushort_t* ATTbf = (ushort_t*)QK; // alias: QK fp32 dead after prep_qk
    // total: 144.75MB

    dim3 blk(256);

    cvt_bf16<<<dim3(M * 2048 / (256 * 8)), blk, 0, stream>>>(x, xbf);
    cvt_tr_bf16<<<dim3(16, 32), blk, 0, stream>>>(w_q_sem, WT + (size_t)0 * 2097152, 2048, 1024);
    cvt_tr_bf16<<<dim3(16, 32), blk, 0, stream>>>(w_k_sem, WT + (size_t)1 * 2097152, 2048, 1024);
    cvt_tr_bf16<<<dim3(16, 32), blk, 0, stream>>>(w_q_geo, WT + (size_t)2 * 2097152, 2048, 1024);
    cvt_tr_bf16<<<dim3(16, 32), blk, 0, stream>>>(w_k_geo, WT + (size_t)3 * 2097152, 2048, 1024);
    gemm_bf16_bt<<<dim3(32, 32), blk, 0, stream>>>(xbf, WT, QK, M, 4096, 2048);
    cvt_tr_bf16<<<dim3(32, 32), blk, 0, stream>>>(w_v, WT, 2048, 2048);
    gemm_bf16_bt<<<dim3(16, 32), blk, 0, stream>>>(xbf, WT, Vb, M, 2048, 2048);

    gate_kernel<<<dim3(M), blk, 0, stream>>>(x, gw, glogit, GATE);
    rope_table<<<dim3(256), blk, 0, stream>>>(ROPETAB);
    prep_qk<<<dim3(M * 16 * 32 / 256), blk, 0, stream>>>(QK, GATE, ROPETAB, Qb, Kb);
    prep_v<<<dim3(T_ / 64, 2, 32), blk, 0, stream>>>(Vb, Vt);

    attn_mfma<<<dim3(T_ / 128, 32), blk, 0, stream>>>(Qb, Kb, Vt, ATTbf);

    cvt_tr_bf16<<<dim3(32, 32), blk, 0, stream>>>(w_out, WT, 2048, 2048);
    gemm_bf16_bt<<<dim3(16, 32), blk, 0, stream>>>(ATTbf, WT, out, M, 2048, 2048);
}

// Round 4
// 552.201 us; speedup vs baseline: 6.7977x; 1.0060x over previous
//
#include <hip/hip_runtime.h>
#include <hip/hip_bf16.h>
#include <math.h>

#define B_ 2
#define T_ 2048
#define D_ 2048
#define H_ 16

typedef __attribute__((ext_vector_type(8))) short bf16x8;
typedef __attribute__((ext_vector_type(4))) float f32x4;
typedef unsigned short ushort_t;

// fp32 -> bf16 bits, round-to-nearest-even
__device__ __forceinline__ ushort_t f2bf(float f) {
    unsigned int u = __float_as_uint(f);
    u += 0x7fffu + ((u >> 16) & 1u);
    return (ushort_t)(u >> 16);
}

__device__ __forceinline__ void gl_lds16(const void* g, void* l) {
    __builtin_amdgcn_global_load_lds(
        (const __attribute__((address_space(1))) void*)g,
        (__attribute__((address_space(3))) void*)l, 16, 0, 0);
}

// ---------------------------------------------------------------------------
// cvt: fp32 row-major -> bf16 bits row-major (8 elems/thread)
// ---------------------------------------------------------------------------
__global__ __launch_bounds__(256) void cvt_bf16(
    const float* __restrict__ in, ushort_t* __restrict__ out)
{
    const int base = (blockIdx.x * 256 + threadIdx.x) * 8;
    const float4 a = *(const float4*)(in + base);
    const float4 b = *(const float4*)(in + base + 4);
    unsigned int r0 = (unsigned int)f2bf(a.x) | ((unsigned int)f2bf(a.y) << 16);
    unsigned int r1 = (unsigned int)f2bf(a.z) | ((unsigned int)f2bf(a.w) << 16);
    unsigned int r2 = (unsigned int)f2bf(b.x) | ((unsigned int)f2bf(b.y) << 16);
    unsigned int r3 = (unsigned int)f2bf(b.z) | ((unsigned int)f2bf(b.w) << 16);
    *(uint4*)(out + base) = make_uint4(r0, r1, r2, r3);
}

// ---------------------------------------------------------------------------
// cvt + transpose: in[K][N] fp32 -> out[N][K] bf16 bits. 64x64 LDS tile.
// ---------------------------------------------------------------------------
__global__ __launch_bounds__(256) void cvt_tr_bf16(
    const float* __restrict__ in, ushort_t* __restrict__ out, int K, int N)
{
    __shared__ float t[64][65];
    const int n0 = blockIdx.x * 64, k0 = blockIdx.y * 64;
    const int tx = threadIdx.x & 63, ty = threadIdx.x >> 6;
#pragma unroll
    for (int i = 0; i < 16; i++) {
        const int r = i * 4 + ty;
        t[r][tx] = in[(size_t)(k0 + r) * N + n0 + tx];
    }
    __syncthreads();
#pragma unroll
    for (int i = 0; i < 16; i++) {
        const int nn = i * 4 + ty;
        out[(size_t)(n0 + nn) * K + k0 + tx] = f2bf(t[tx][nn]);
    }
}

// ---------------------------------------------------------------------------
// Shared GEMM core (m97 structure): acc = A[M,K] @ BT[N,K]^T on a 128x128
// tile at (row0, col0). BK=32, 4 waves, 16x16x32 bf16 MFMA.
// ---------------------------------------------------------------------------
__device__ __forceinline__ void gemm_core(
    const ushort_t* __restrict__ Ab, const ushort_t* __restrict__ BTb,
    int K, int row0, int col0,
    ushort_t* As, ushort_t* Bs, f32x4 (&acc)[4][4], int w, int lane)
{
    const int lm = lane & 15, lk = (lane >> 4) << 3;
    const int wr = w >> 1, wc = w & 1;
#pragma unroll
    for (int m = 0; m < 4; m++)
#pragma unroll
        for (int n = 0; n < 4; n++) {
            acc[m][n][0] = 0.f; acc[m][n][1] = 0.f;
            acc[m][n][2] = 0.f; acc[m][n][3] = 0.f;
        }

    for (int k0 = 0; k0 < K; k0 += 32) {
        __syncthreads();
#pragma unroll
        for (int i = 0; i < 2; i++) {
            const int chunk = i * 4 + w;
            const int idx = chunk * 64 + lane;
            const int r = idx >> 2;
            const int c = (idx & 3) << 3;
            gl_lds16(Ab + (size_t)(row0 + r) * K + k0 + c, As + chunk * 512);
            gl_lds16(BTb + (size_t)(col0 + r) * K + k0 + c, Bs + chunk * 512);
        }
        __syncthreads();

        bf16x8 av[4], bv[4];
#pragma unroll
        for (int m = 0; m < 4; m++)
            av[m] = *(const bf16x8*)&As[(wr * 64 + m * 16 + lm) * 32 + lk];
#pragma unroll
        for (int n = 0; n < 4; n++)
            bv[n] = *(const bf16x8*)&Bs[(wc * 64 + n * 16 + lm) * 32 + lk];
#pragma unroll
        for (int m = 0; m < 4; m++)
#pragma unroll
            for (int n = 0; n < 4; n++)
                acc[m][n] = __builtin_amdgcn_mfma_f32_16x16x32_bf16(
                    av[m], bv[n], acc[m][n], 0, 0, 0);
    }
}

// bijective XCD swizzle (nwg % 8 == 0 for all our grids)
__device__ __forceinline__ void xcd_tile(int& row0, int& col0)
{
    const int o = blockIdx.y * gridDim.x + blockIdx.x;
    const int nwg = gridDim.x * gridDim.y;
    const int s = (o & 7) * (nwg >> 3) + (o >> 3);
    col0 = (s % gridDim.x) << 7;
    row0 = (s / gridDim.x) << 7;
}

// ---------------------------------------------------------------------------
// gemm_bf16_bt: fp32 row-major C (final output projection)
// ---------------------------------------------------------------------------
__global__ __launch_bounds__(256) void gemm_bf16_bt(
    const ushort_t* __restrict__ Ab, const ushort_t* __restrict__ BTb,
    float* __restrict__ C, int N, int K)
{
    __shared__ ushort_t As[4096];
    __shared__ ushort_t Bs[4096];
    const int tid = threadIdx.x;
    const int w = tid >> 6, lane = tid & 63;
    int row0, col0;
    xcd_tile(row0, col0);
    f32x4 acc[4][4];
    gemm_core(Ab, BTb, K, row0, col0, As, Bs, acc, w, lane);

    const int wr = w >> 1, wc = w & 1;
    const int lm = lane & 15;
#pragma unroll
    for (int m = 0; m < 4; m++) {
        const int rowb = row0 + wr * 64 + m * 16 + ((lane >> 4) << 2);
#pragma unroll
        for (int n = 0; n < 4; n++) {
            const int col = col0 + wc * 64 + n * 16 + lm;
#pragma unroll
            for (int r = 0; r < 4; r++)
                C[(size_t)(rowb + r) * N + col] = acc[m][n][r];
        }
    }
}

// ---------------------------------------------------------------------------
// gemm_bf16_bf16out: bf16 row-major C (V projection)
// ---------------------------------------------------------------------------
__global__ __launch_bounds__(256) void gemm_bf16_bf16out(
    const ushort_t* __restrict__ Ab, const ushort_t* __restrict__ BTb,
    ushort_t* __restrict__ C, int N, int K)
{
    __shared__ ushort_t As[4096];
    __shared__ ushort_t Bs[4096];
    const int tid = threadIdx.x;
    const int w = tid >> 6, lane = tid & 63;
    int row0, col0;
    xcd_tile(row0, col0);
    f32x4 acc[4][4];
    gemm_core(Ab, BTb, K, row0, col0, As, Bs, acc, w, lane);

    const int wr = w >> 1, wc = w & 1;
    const int lm = lane & 15;
#pragma unroll
    for (int m = 0; m < 4; m++) {
        const int rowb = row0 + wr * 64 + m * 16 + ((lane >> 4) << 2);
#pragma unroll
        for (int n = 0; n < 4; n++) {
            const int col = col0 + wc * 64 + n * 16 + lm;
#pragma unroll
            for (int r = 0; r < 4; r++)
                C[(size_t)(rowb + r) * N + col] = f2bf(acc[m][n][r]);
        }
    }
}

// ---------------------------------------------------------------------------
// gemm_qk_fused: QK projection with fused rope/gate/bf16/K-swizzle epilogue.
// N=4096 fixed: cols [0,1024)=qs, [1024,2048)=ks, [2048,3072)=qg, [3072,4096)=kg.
// Writes Qb[bh][t][128] (gate-scaled, rope'd, x1/8) and
//        Kb[bh][t][d ^ ((t&7)<<3)] (rope'd, LDS-swizzled).
// ---------------------------------------------------------------------------
__global__ __launch_bounds__(256) void gemm_qk_fused(
    const ushort_t* __restrict__ Ab, const ushort_t* __restrict__ BTb,
    const float* __restrict__ GATE, const float2* __restrict__ tab,
    ushort_t* __restrict__ Qb, ushort_t* __restrict__ Kb, int K)
{
    __shared__ ushort_t As[4096];
    __shared__ ushort_t Bs[4096];
    const int tid = threadIdx.x;
    const int w = tid >> 6, lane = tid & 63;
    int row0, col0;
    xcd_tile(row0, col0);
    f32x4 acc[4][4];
    gemm_core(Ab, BTb, K, row0, col0, As, Bs, acc, w, lane);

    const int wr = w >> 1, wc = w & 1;
    const int lm = lane & 15, lg = lane >> 4;
    const int col_base = col0 + wc * 64;     // 64-aligned -> one head, one region
    const int region = col_base >> 10;       // 0=qs 1=ks 2=qg 3=kg
    const int h = (col_base >> 6) & 15;

#pragma unroll
    for (int m = 0; m < 4; m++) {
        const int rbase = row0 + wr * 64 + m * 16 + (lg << 2);
#pragma unroll
        for (int r = 0; r < 4; r++) {
            const int row = rbase + r;              // global token row
            const int t = row & (T_ - 1);
            const int bq = row >> 11;
            const size_t obase = ((size_t)(bq * 16 + h) * 2048 + t) * 128;
            if (region == 0) {                      // qs: scale by g/8
                const float sc = GATE[row * 16 + h] * 0.125f;
#pragma unroll
                for (int n = 0; n < 4; n++)
                    Qb[obase + n * 16 + lm] = f2bf(acc[m][n][r] * sc);
            } else if (region == 1) {               // ks: raw, swizzled
                const int sw = (t & 7) << 3;
#pragma unroll
                for (int n = 0; n < 4; n++)
                    Kb[obase + ((n * 16 + lm) ^ sw)] = f2bf(acc[m][n][r]);
            } else if (region == 2) {               // qg: rope + (1-g)/8
                const float sc = (1.f - GATE[row * 16 + h]) * 0.125f;
#pragma unroll
                for (int n = 0; n < 2; n++) {
                    const int j = n * 16 + lm;      // 0..31
                    const float2 cs = tab[t * 32 + j];
                    const float x1 = acc[m][n][r], x2 = acc[m][n + 2][r];
                    Qb[obase + 64 + j] = f2bf((x1 * cs.x - x2 * cs.y) * sc);
                    Qb[obase + 96 + j] = f2bf((x2 * cs.x + x1 * cs.y) * sc);
                }
            } else {                                // kg: rope, swizzled
                const int sw = (t & 7) << 3;
#pragma unroll
                for (int n = 0; n < 2; n++) {
                    const int j = n * 16 + lm;
                    const float2 cs = tab[t * 32 + j];
                    const float x1 = acc[m][n][r], x2 = acc[m][n + 2][r];
                    Kb[obase + ((64 + j) ^ sw)] = f2bf(x1 * cs.x - x2 * cs.y);
                    Kb[obase + ((96 + j) ^ sw)] = f2bf(x2 * cs.x + x1 * cs.y);
                }
            }
        }
    }
}

// ---------------------------------------------------------------------------
// gate[row,h] = sigmoid(gate_logit[h] + x[row,:] . gate_w[:,h])
// ---------------------------------------------------------------------------
__global__ __launch_bounds__(256) void gate_kernel(
    const float* __restrict__ x, const float* __restrict__ gw,
    const float* __restrict__ glogit, float* __restrict__ gate)
{
    __shared__ float xs[2048];
    __shared__ float red[256];
    const int row = blockIdx.x, tid = threadIdx.x;
#pragma unroll
    for (int i = 0; i < 8; i++) xs[i * 256 + tid] = x[(size_t)row * 2048 + i * 256 + tid];
    __syncthreads();
    const int h = tid & 15, chunk = tid >> 4;
    float acc = 0.f;
#pragma unroll 4
    for (int d0 = 0; d0 < 128; d0++) {
        const int d = chunk * 128 + d0;
        acc += xs[d] * gw[d * 16 + h];
    }
    red[tid] = acc;
    __syncthreads();
    for (int st = 8; st >= 1; st >>= 1) {
        if (chunk < st) red[chunk * 16 + h] += red[(chunk + st) * 16 + h];
        __syncthreads();
    }
    if (tid < 16) gate[row * 16 + tid] = 1.f / (1.f + expf(-(glogit[tid] + red[tid])));
}

// ---------------------------------------------------------------------------
// rope cos/sin table: tab[t*32+j] = (cos, sin)(t * 10000^(-j/32))
// ---------------------------------------------------------------------------
__global__ __launch_bounds__(256) void rope_table(float2* __restrict__ tab)
{
    const int gid = blockIdx.x * 256 + threadIdx.x;  // 65536
    const int j = gid & 31, t = gid >> 5;
    const float invf = exp2f((float)j * -0.41524101186091903f);
    const float ang = (float)t * invf;
    tab[gid] = make_float2(cosf(ang), sinf(ang));
}

// ---------------------------------------------------------------------------
// prep_v: Vbb bf16 [row][h*128+dv] -> Vt[bh][dv][t swizzled] bf16 (V^T).
// ---------------------------------------------------------------------------
__global__ __launch_bounds__(256) void prep_v(
    const ushort_t* __restrict__ Vbb, ushort_t* __restrict__ Vt)
{
    __shared__ ushort_t tile[64][65];
    const int t0 = blockIdx.x * 64, dv0 = blockIdx.y * 64, bh = blockIdx.z;
    const int b = bh >> 4, h = bh & 15;
    const int c = threadIdx.x & 63, rq = threadIdx.x >> 6;
#pragma unroll
    for (int i = 0; i < 16; i++) {
        const int r = i * 4 + rq;
        tile[r][c] = Vbb[(size_t)(b * T_ + t0 + r) * 2048 + h * 128 + dv0 + c];
    }
    __syncthreads();
#pragma unroll
    for (int i = 0; i < 16; i++) {
        const int dvr = i * 4 + rq;
        const int dv = dv0 + dvr;
        Vt[((size_t)bh * 128 + dv) * 2048 + t0 + (c ^ ((dv & 7) << 3))] = tile[c][dvr];
    }
}

// ---------------------------------------------------------------------------
// MFMA flash attention. QBLK=128 (4 waves x 32 rows), KBLK=64, d=dv=128.
// Heavy-first: t0 reversed so long blocks dispatch first (load balance).
// ---------------------------------------------------------------------------
__global__ __launch_bounds__(256, 2) void attn_mfma(
    const ushort_t* __restrict__ Qb, const ushort_t* __restrict__ Kb,
    const ushort_t* __restrict__ Vt, ushort_t* __restrict__ OUT)
{
    __shared__ ushort_t Ks[64 * 128];   // [key][d_sw]  16KB
    __shared__ ushort_t Vs[128 * 64];   // [dv][k_sw]   16KB
    __shared__ ushort_t Ps[4][32 * 72]; // per-wave P, row stride 72  18KB

    const int tid = threadIdx.x;
    const int w = tid >> 6, l = tid & 63;
    const int lg = l >> 4, lm = l & 15;
    const int bh = blockIdx.y;
    const int t0 = (gridDim.x - 1 - blockIdx.x) << 7;   // heavy blocks first
    const size_t hb = (size_t)bh * 2048 * 128;

    bf16x8 qf[2][4];
#pragma unroll
    for (int m = 0; m < 2; m++)
#pragma unroll
        for (int ks = 0; ks < 4; ks++)
            qf[m][ks] = *(const bf16x8*)(Qb + hb +
                (size_t)(t0 + w * 32 + m * 16 + lm) * 128 + ks * 32 + lg * 8);

    f32x4 o[2][8];
    float mi[2][4], li[2][4];
#pragma unroll
    for (int m = 0; m < 2; m++) {
#pragma unroll
        for (int r = 0; r < 4; r++) { mi[m][r] = -1e30f; li[m][r] = 0.f; }
#pragma unroll
        for (int nv = 0; nv < 8; nv++) {
            o[m][nv][0] = 0.f; o[m][nv][1] = 0.f; o[m][nv][2] = 0.f; o[m][nv][3] = 0.f;
        }
    }

    ushort_t* pw = &Ps[w][0];
    const int nkt = (t0 >> 6) + 2;

    for (int kt = 0; kt < nkt; kt++) {
        const int s0 = kt << 6;
        __syncthreads();
#pragma unroll
        for (int rr = 0; rr < 4; rr++) {
            const int chunk = rr * 4 + w;
            gl_lds16(Kb + hb + (size_t)(s0 + chunk * 4 + lg) * 128 + lm * 8,
                     Ks + chunk * 512);
        }
#pragma unroll
        for (int rr = 0; rr < 4; rr++) {
            const int chunk = rr * 4 + w;
            gl_lds16(Vt + hb + (size_t)(chunk * 8 + (l >> 3)) * 2048 + s0 + (l & 7) * 8,
                     Vs + chunk * 512);
        }
        __syncthreads();

        // ---- S = Q . K^T ----
        f32x4 sacc[2][4];
#pragma unroll
        for (int m = 0; m < 2; m++)
#pragma unroll
            for (int n = 0; n < 4; n++) {
                sacc[m][n][0] = 0.f; sacc[m][n][1] = 0.f;
                sacc[m][n][2] = 0.f; sacc[m][n][3] = 0.f;
            }
#pragma unroll
        for (int ks = 0; ks < 4; ks++) {
            bf16x8 bfr[4];
#pragma unroll
            for (int n = 0; n < 4; n++) {
                const int key = n * 16 + lm;
                const int d = ks * 32 + lg * 8;
                bfr[n] = *(const bf16x8*)&Ks[key * 128 + (d ^ ((key & 7) << 3))];
            }
#pragma unroll
            for (int m = 0; m < 2; m++)
#pragma unroll
                for (int n = 0; n < 4; n++)
                    sacc[m][n] = __builtin_amdgcn_mfma_f32_16x16x32_bf16(
                        qf[m][ks], bfr[n], sacc[m][n], 0, 0, 0);
        }

        if (kt >= nkt - 2) {
#pragma unroll
            for (int m = 0; m < 2; m++)
#pragma unroll
                for (int n = 0; n < 4; n++)
#pragma unroll
                    for (int r = 0; r < 4; r++) {
                        const int rowt = t0 + w * 32 + m * 16 + lg * 4 + r;
                        const int colt = s0 + n * 16 + lm;
                        if (colt > rowt) sacc[m][n][r] = -1e30f;
                    }
        }

        // ---- online softmax + P -> LDS (bf16) ----
#pragma unroll
        for (int m = 0; m < 2; m++) {
#pragma unroll
            for (int r = 0; r < 4; r++) {
                float mt = fmaxf(fmaxf(sacc[m][0][r], sacc[m][1][r]),
                                 fmaxf(sacc[m][2][r], sacc[m][3][r]));
                mt = fmaxf(mt, __shfl_xor(mt, 1));
                mt = fmaxf(mt, __shfl_xor(mt, 2));
                mt = fmaxf(mt, __shfl_xor(mt, 4));
                mt = fmaxf(mt, __shfl_xor(mt, 8));
                const float mnew = fmaxf(mi[m][r], mt);
                const float alpha = __expf(mi[m][r] - mnew);
                float rs = 0.f;
#pragma unroll
                for (int n = 0; n < 4; n++) {
                    const float p = __expf(sacc[m][n][r] - mnew);
                    sacc[m][n][r] = p;
                    rs += p;
                }
                rs += __shfl_xor(rs, 1);
                rs += __shfl_xor(rs, 2);
                rs += __shfl_xor(rs, 4);
                rs += __shfl_xor(rs, 8);
                li[m][r] = li[m][r] * alpha + rs;
                mi[m][r] = mnew;
#pragma unroll
                for (int nv = 0; nv < 8; nv++) o[m][nv][r] *= alpha;
#pragma unroll
                for (int n = 0; n < 4; n++)
                    pw[(m * 16 + lg * 4 + r) * 72 + n * 16 + lm] = f2bf(sacc[m][n][r]);
            }
        }

        // ---- O += P @ V ----
#pragma unroll
        for (int ks2 = 0; ks2 < 2; ks2++) {
            bf16x8 pa[2];
#pragma unroll
            for (int m = 0; m < 2; m++)
                pa[m] = *(const bf16x8*)&pw[(m * 16 + lm) * 72 + ks2 * 32 + lg * 8];
#pragma unroll
            for (int nv = 0; nv < 8; nv++) {
                const int dv = nv * 16 + lm;
                const bf16x8 vb = *(const bf16x8*)&Vs[dv * 64 +
                    ((ks2 * 32 + lg * 8) ^ ((dv & 7) << 3))];
#pragma unroll
                for (int m = 0; m < 2; m++)
                    o[m][nv] = __builtin_amdgcn_mfma_f32_16x16x32_bf16(
                        pa[m], vb, o[m][nv], 0, 0, 0);
            }
        }
    }

    const int b = bh >> 4, h = bh & 15;
#pragma unroll
    for (int m = 0; m < 2; m++)
#pragma unroll
        for (int r = 0; r < 4; r++) {
            const float inv = 1.f / li[m][r];
            const int trow = t0 + w * 32 + m * 16 + lg * 4 + r;
            ushort_t* orow = OUT + (size_t)(b * T_ + trow) * 2048 + h * 128 + lm;
#pragma unroll
            for (int nv = 0; nv < 8; nv++)
                orow[nv * 16] = f2bf(o[m][nv][r] * inv);
        }
}

// ---------------------------------------------------------------------------
extern "C" void kernel_launch(void* const* d_in, const int* in_sizes, int n_in,
                              void* d_out, int out_size, void* d_ws, size_t ws_size,
                              hipStream_t stream)
{
    const float* x       = (const float*)d_in[0];
    const float* w_q_sem = (const float*)d_in[1];
    const float* w_k_sem = (const float*)d_in[2];
    const float* w_q_geo = (const float*)d_in[3];
    const float* w_k_geo = (const float*)d_in[4];
    const float* w_v     = (const float*)d_in[5];
    const float* w_out   = (const float*)d_in[6];
    const float* glogit  = (const float*)d_in[7];
    const float* gw      = (const float*)d_in[8];
    float* out = (float*)d_out;

    const int M = B_ * T_;  // 4096
    const size_t MB8 = (size_t)8 * 1024 * 1024;

    // workspace (96.75 MB):
    ushort_t* xbf = (ushort_t*)d_ws;       // [4096][2048] bf16
    ushort_t* WT  = xbf + MB8;             // up to [4096][2048] bf16 (weightsT)
    ushort_t* Qb  = WT + MB8;              // [bh][t][128]
    ushort_t* Kb  = Qb + MB8;              // [bh][t][128] swizzled
    ushort_t* Vt  = Kb + MB8;              // [bh][128][2048] swizzled V^T
    ushort_t* Vbb = Vt + MB8;              // [4096][2048] bf16 V (row-major)
    float* GATE   = (float*)(Vbb + MB8);   // [4096][16]
    float2* TAB   = (float2*)(GATE + 65536); // [2048][32]
    ushort_t* ATTbf = Vbb;                 // alias: Vbb dead after prep_v

    dim3 blk(256);

    cvt_bf16<<<dim3(M * 2048 / (256 * 8)), blk, 0, stream>>>(x, xbf);
    cvt_tr_bf16<<<dim3(16, 32), blk, 0, stream>>>(w_q_sem, WT + (size_t)0 * 2097152, 2048, 1024);
    cvt_tr_bf16<<<dim3(16, 32), blk, 0, stream>>>(w_k_sem, WT + (size_t)1 * 2097152, 2048, 1024);
    cvt_tr_bf16<<<dim3(16, 32), blk, 0, stream>>>(w_q_geo, WT + (size_t)2 * 2097152, 2048, 1024);
    cvt_tr_bf16<<<dim3(16, 32), blk, 0, stream>>>(w_k_geo, WT + (size_t)3 * 2097152, 2048, 1024);
    gate_kernel<<<dim3(M), blk, 0, stream>>>(x, gw, glogit, GATE);
    rope_table<<<dim3(256), blk, 0, stream>>>(TAB);

    // fused QK projection + rope + gate + swizzle -> Qb, Kb
    gemm_qk_fused<<<dim3(32, 32), blk, 0, stream>>>(xbf, WT, GATE, TAB, Qb, Kb, 2048);

    // V projection (bf16 out) + transpose/swizzle
    cvt_tr_bf16<<<dim3(32, 32), blk, 0, stream>>>(w_v, WT, 2048, 2048);
    gemm_bf16_bf16out<<<dim3(16, 32), blk, 0, stream>>>(xbf, WT, Vbb, 2048, 2048);
    prep_v<<<dim3(T_ / 64, 2, 32), blk, 0, stream>>>(Vbb, Vt);

    attn_mfma<<<dim3(T_ / 128, 32), blk, 0, stream>>>(Qb, Kb, Vt, ATTbf);

    cvt_tr_bf16<<<dim3(32, 32), blk, 0, stream>>>(w_out, WT, 2048, 2048);
    gemm_bf16_bt<<<dim3(16, 32), blk, 0, stream>>>(ATTbf, WT, out, 2048, 2048);
}